// Round 1
// baseline (13315.028 us; speedup 1.0000x reference)
//
#include <hip/hip_runtime.h>
#include <math.h>

#define Bq 512
#define Tq 128
#define Fq 64
#define Uq 1024
#define OSTEPS 24

#define BM 64
#define BK 32

__device__ __forceinline__ float sigmoidf_(float x) {
    return 1.0f / (1.0f + __expf(-x));
}
__device__ __forceinline__ float tanhf_(float x) {
    // tanh(x) = 2/(1+exp(-2x)) - 1 ; saturates correctly for large |x|
    return 2.0f / (1.0f + __expf(-2.0f * x)) - 1.0f;
}

// Fused LSTM step: z = x @ Wx + h @ Wh + b  (gates interleaved per-unit at staging),
// then i,f,g,o nonlinearities, c/h update.
// Grid: 256 blocks (8 batch tiles x 32 unit tiles), 256 threads.
__global__ __launch_bounds__(256)
void lstm_step(const float* __restrict__ h_in,   // [B][U]
               const float* __restrict__ x,      // [B][...] row stride xstride, F cols used
               long xstride,
               const float* __restrict__ Wh,     // [U][4U] cols = g*U + u
               const float* __restrict__ Wx,     // [F][4U]
               const float* __restrict__ bias,   // [4U]
               float* __restrict__ h_out,        // [B][U]
               float* __restrict__ c)            // [B][U] (in/out)
{
    __shared__ float As[BM][BK];      // [64][32]  A rows (h then x)
    __shared__ float Ws[BK][128];     // [32][128] cols = ul*4 + gate

    const int tid = threadIdx.x;
    const int bm  = blockIdx.x >> 5;   // 0..7   batch tile
    const int bu  = blockIdx.x & 31;   // 0..31  unit tile
    const int rb0 = bm * BM;
    const int u0  = bu * 32;

    const int cg = tid & 31;   // unit within tile (owns 4 gate cols)
    const int rg = tid >> 5;   // row group: rows rg*8 .. rg*8+7

    const int a_r = tid >> 3;        // 0..31 (loads rows a_r and a_r+32)
    const int a_k = (tid & 7) * 4;   // 0,4,...,28

    float acc[8][4];
#pragma unroll
    for (int j = 0; j < 8; ++j)
#pragma unroll
        for (int g = 0; g < 4; ++g) acc[j][g] = 0.0f;

    for (int kk = 0; kk < Uq + Fq; kk += BK) {
        // ---- global loads to registers ----
        const float* asrc;
        long rstride;
        int kbase;
        if (kk < Uq) { asrc = h_in; rstride = Uq;     kbase = kk; }
        else         { asrc = x;    rstride = xstride; kbase = kk - Uq; }
        float4 v0 = *(const float4*)(asrc + (long)(rb0 + a_r)      * rstride + kbase + a_k);
        float4 v1 = *(const float4*)(asrc + (long)(rb0 + a_r + 32) * rstride + kbase + a_k);

        const float* wsrc = (kk < Uq) ? (Wh + (long)kk * (4 * Uq))
                                      : (Wx + (long)(kk - Uq) * (4 * Uq));
        float4 wv[4];
#pragma unroll
        for (int j = 0; j < 4; ++j) {
            const int k = (tid >> 5) + j * 8;
            const float* wp = wsrc + (long)k * (4 * Uq) + u0 + cg;
            wv[j].x = wp[0 * Uq];
            wv[j].y = wp[1 * Uq];
            wv[j].z = wp[2 * Uq];
            wv[j].w = wp[3 * Uq];
        }

        __syncthreads();   // previous tile fully consumed
        *(float4*)&As[a_r][a_k]      = v0;
        *(float4*)&As[a_r + 32][a_k] = v1;
#pragma unroll
        for (int j = 0; j < 4; ++j) {
            const int k = (tid >> 5) + j * 8;
            *(float4*)&Ws[k][cg * 4] = wv[j];
        }
        __syncthreads();

        // ---- compute ----
#pragma unroll 8
        for (int k = 0; k < BK; ++k) {
            float4 w = *(const float4*)&Ws[k][cg * 4];
#pragma unroll
            for (int j = 0; j < 8; ++j) {
                float a = As[rg * 8 + j][k];
                acc[j][0] = fmaf(a, w.x, acc[j][0]);
                acc[j][1] = fmaf(a, w.y, acc[j][1]);
                acc[j][2] = fmaf(a, w.z, acc[j][2]);
                acc[j][3] = fmaf(a, w.w, acc[j][3]);
            }
        }
    }

    // ---- epilogue: gates + state update ----
    const int u = u0 + cg;
    const float bi = bias[0 * Uq + u];
    const float bf = bias[1 * Uq + u];
    const float bg = bias[2 * Uq + u];
    const float bo = bias[3 * Uq + u];
#pragma unroll
    for (int j = 0; j < 8; ++j) {
        const int row = rb0 + rg * 8 + j;
        const long idx = (long)row * Uq + u;
        float zi = acc[j][0] + bi;
        float zf = acc[j][1] + bf;
        float zg = acc[j][2] + bg;
        float zo = acc[j][3] + bo;
        float ig = sigmoidf_(zi);
        float fg = sigmoidf_(zf);
        float gg = tanhf_(zg);
        float og = sigmoidf_(zo);
        float cn = fg * c[idx] + ig * gg;
        c[idx] = cn;
        h_out[idx] = og * tanhf_(cn);
    }
}

// Dense readout: p = h @ Wd + bd ; also scatter into out[:, step, :]
// Grid: 128 blocks x 256 threads (4 rows x 64 cols per block)
__global__ __launch_bounds__(256)
void readout(const float* __restrict__ h,   // [B][U]
             const float* __restrict__ Wd,  // [U][F]
             const float* __restrict__ bd,  // [F]
             float* __restrict__ p,         // [B][F]
             float* __restrict__ out,       // [B][OSTEPS][F]
             int step)
{
    const int f = threadIdx.x & 63;
    const int r = blockIdx.x * 4 + (threadIdx.x >> 6);
    const float* hp = h + (long)r * Uq;
    float a = 0.0f;
#pragma unroll 8
    for (int k = 0; k < Uq; ++k)
        a = fmaf(hp[k], Wd[(long)k * Fq + f], a);
    a += bd[f];
    p[(long)r * Fq + f] = a;
    out[((long)r * OSTEPS + step) * Fq + f] = a;
}

__global__ void zero2(float* __restrict__ a, float* __restrict__ b, int n) {
    int i = blockIdx.x * 256 + threadIdx.x;
    if (i < n) { a[i] = 0.0f; b[i] = 0.0f; }
}

extern "C" void kernel_launch(void* const* d_in, const int* in_sizes, int n_in,
                              void* d_out, int out_size, void* d_ws, size_t ws_size,
                              hipStream_t stream) {
    const float* inputs = (const float*)d_in[0];  // [B][T][F]
    const float* Wx     = (const float*)d_in[1];  // [F][4U]
    const float* Wh     = (const float*)d_in[2];  // [U][4U]
    const float* b      = (const float*)d_in[3];  // [4U]
    const float* Wd     = (const float*)d_in[4];  // [U][F]
    const float* bd     = (const float*)d_in[5];  // [F]
    float* out = (float*)d_out;

    float* ws = (float*)d_ws;
    float* h0 = ws;                    // 512*1024
    float* h1 = h0 + Bq * Uq;          // 512*1024
    float* c  = h1 + Bq * Uq;          // 512*1024
    float* p  = c  + Bq * Uq;          // 512*64

    zero2<<<(Bq * Uq + 255) / 256, 256, 0, stream>>>(h0, c, Bq * Uq);

    float* hc = h0;
    float* hn = h1;
    // ---- warmup over T timesteps ----
    for (int t = 0; t < Tq; ++t) {
        lstm_step<<<256, 256, 0, stream>>>(hc, inputs + (long)t * Fq, (long)Tq * Fq,
                                           Wh, Wx, b, hn, c);
        float* tmp = hc; hc = hn; hn = tmp;
    }
    // ---- first prediction ----
    readout<<<Bq / 4, 256, 0, stream>>>(hc, Wd, bd, p, out, 0);
    // ---- autoregressive decode ----
    for (int s = 1; s < OSTEPS; ++s) {
        lstm_step<<<256, 256, 0, stream>>>(hc, p, (long)Fq, Wh, Wx, b, hn, c);
        float* tmp = hc; hc = hn; hn = tmp;
        readout<<<Bq / 4, 256, 0, stream>>>(hc, Wd, bd, p, out, s);
    }
}

// Round 2
// 3809.698 us; speedup vs baseline: 3.4950x; 3.4950x over previous
//
#include <hip/hip_runtime.h>
#include <math.h>

#define Bq 512
#define Tq 128
#define Fq 64
#define Uq 1024
#define OSTEPS 24

// K = Uq + Fq = 1088 = 17 chunks of 64 = 68 sub-chunks of 16
#define NKC16 68
#define NCH 17

typedef __bf16 bf16x8 __attribute__((ext_vector_type(8)));
typedef float f32x16 __attribute__((ext_vector_type(16)));
typedef float f32x4 __attribute__((ext_vector_type(4)));

__device__ __forceinline__ float sigmoidf_(float x) {
    return 1.0f / (1.0f + __expf(-x));
}
__device__ __forceinline__ float tanhf_(float x) {
    return 2.0f / (1.0f + __expf(-2.0f * x)) - 1.0f;
}

// ---------------------------------------------------------------------------
// Pack Wh [1024][4096] + Wx [64][4096] (fp32, z-col = g*1024+u) into B-fragment
// order for v_mfma_f32_32x32x16_bf16, split hi/lo bf16.
// Layout: Bp[(gcol32*68 + kc16)*64 + lane] = 8 bf16, where
//   gcol32 = g*32 + ublk (ublk = z-col/32 within gate), col = lane&31,
//   k = kc16*16 + (lane>>5)*8 + j   (k<1024 -> Wh row k; else Wx row k-1024)
// ---------------------------------------------------------------------------
__global__ __launch_bounds__(256)
void pack_w(const float* __restrict__ Wh, const float* __restrict__ Wx,
            bf16x8* __restrict__ BpH, bf16x8* __restrict__ BpL)
{
    long id = (long)blockIdx.x * 256 + threadIdx.x;   // 128*68*64 = 557056 slots
    int lane = (int)(id & 63);
    long rest = id >> 6;
    int kc16 = (int)(rest % NKC16);
    int gcol = (int)(rest / NKC16);                   // 0..127
    int col = (gcol >> 5) * Uq + (gcol & 31) * 32 + (lane & 31);
    int k0 = kc16 * 16 + (lane >> 5) * 8;
    bf16x8 hv, lv;
#pragma unroll
    for (int j = 0; j < 8; ++j) {
        int k = k0 + j;
        float v = (k < Uq) ? Wh[(long)k * (4 * Uq) + col]
                           : Wx[(long)(k - Uq) * (4 * Uq) + col];
        __bf16 h_ = (__bf16)v;
        hv[j] = h_;
        lv[j] = (__bf16)(v - (float)h_);
    }
    BpH[id] = hv;
    BpL[id] = lv;
}

// ---------------------------------------------------------------------------
// Fused LSTM step with MFMA (bf16x3 split).
// Block: 32 batch rows x 64 units. 4 waves; wave w computes gate w.
// Grid: 256 blocks = 16 M-tiles x 16 U-tiles (1 per CU).
// ---------------------------------------------------------------------------
#define LOADB(Bh, Bl, c) do {                                                  \
    _Pragma("unroll")                                                          \
    for (int kc = 0; kc < 4; ++kc) {                                           \
        _Pragma("unroll")                                                      \
        for (int nf = 0; nf < 2; ++nf) {                                       \
            long idx_ = ((long)((w * 32 + bu * 2 + nf) * NKC16 + ((c) * 4 + kc))) * 64 + l; \
            Bh[kc][nf] = BpH[idx_];                                            \
            Bl[kc][nf] = BpL[idx_];                                            \
        }                                                                      \
    }                                                                          \
} while (0)

#define LOADA(c) do {                                                          \
    const float* src_ = ((c) < 16)                                            \
        ? (h_in + (long)(row0 + srow) * Uq + (c) * 64 + kg8 * 8)               \
        : (xsrc + (long)(row0 + srow) * xstride + kg8 * 8);                    \
    sa0 = *(const f32x4*)src_;                                                 \
    sa1 = *(const f32x4*)(src_ + 4);                                           \
} while (0)

#define WRITEA(nb) do {                                                        \
    bf16x8 hv_, lv_;                                                           \
    _Pragma("unroll")                                                          \
    for (int j = 0; j < 4; ++j) {                                              \
        float v_ = sa0[j]; __bf16 h_ = (__bf16)v_;                             \
        hv_[j] = h_; lv_[j] = (__bf16)(v_ - (float)h_);                        \
    }                                                                          \
    _Pragma("unroll")                                                          \
    for (int j = 0; j < 4; ++j) {                                              \
        float v_ = sa1[j]; __bf16 h_ = (__bf16)v_;                             \
        hv_[4 + j] = h_; lv_[4 + j] = (__bf16)(v_ - (float)h_);                \
    }                                                                          \
    As[nb][skc][0][slane] = hv_;                                               \
    As[nb][skc][1][slane] = lv_;                                               \
} while (0)

#define COMPUTE(cb, Bh, Bl) do {                                               \
    _Pragma("unroll")                                                          \
    for (int kc = 0; kc < 4; ++kc) {                                           \
        bf16x8 ah_ = As[cb][kc][0][l];                                         \
        bf16x8 al_ = As[cb][kc][1][l];                                         \
        acc0 = __builtin_amdgcn_mfma_f32_32x32x16_bf16(ah_, Bh[kc][0], acc0, 0, 0, 0); \
        acc0 = __builtin_amdgcn_mfma_f32_32x32x16_bf16(ah_, Bl[kc][0], acc0, 0, 0, 0); \
        acc0 = __builtin_amdgcn_mfma_f32_32x32x16_bf16(al_, Bh[kc][0], acc0, 0, 0, 0); \
        acc1 = __builtin_amdgcn_mfma_f32_32x32x16_bf16(ah_, Bh[kc][1], acc1, 0, 0, 0); \
        acc1 = __builtin_amdgcn_mfma_f32_32x32x16_bf16(ah_, Bl[kc][1], acc1, 0, 0, 0); \
        acc1 = __builtin_amdgcn_mfma_f32_32x32x16_bf16(al_, Bh[kc][1], acc1, 0, 0, 0); \
    }                                                                          \
} while (0)

__global__ __launch_bounds__(256, 1)
void lstm_step(const float* __restrict__ h_in,   // [512][1024] fp32
               const float* __restrict__ xsrc,   // row base; 64 cols used; stride xstride
               long xstride,
               const bf16x8* __restrict__ BpH,
               const bf16x8* __restrict__ BpL,
               const float* __restrict__ bias,   // [4096]
               float* __restrict__ h_out,        // [512][1024]
               float* __restrict__ c_st)         // [512][1024] in/out
{
    __shared__ bf16x8 As[2][4][2][64];   // [dbuf][kc16][hi/lo][lane] : 16 KB
    __shared__ float zs[4][32][68];      // gate-exchange, padded stride  : 34.8 KB

    const int tid = threadIdx.x;
    const int l   = tid & 63;
    const int w   = tid >> 6;            // wave = gate 0..3
    const int bm  = (int)blockIdx.x >> 4;
    const int bu  = (int)blockIdx.x & 15;
    const int row0 = bm * 32;

    // staging decomposition: thread handles 8 consecutive k of one row
    const int srow  = tid & 31;
    const int kg8   = tid >> 5;          // 0..7
    const int skc   = kg8 >> 1;
    const int slane = (kg8 & 1) * 32 + srow;

    f32x16 acc0, acc1;
#pragma unroll
    for (int i = 0; i < 16; ++i) { acc0[i] = 0.0f; acc1[i] = 0.0f; }

    bf16x8 BhA[4][2], BlA[4][2], BhB[4][2], BlB[4][2];
    f32x4 sa0, sa1;

    // prologue: chunk 0
    LOADA(0);
    LOADB(BhA, BlA, 0);
    WRITEA(0);
    __syncthreads();

#pragma unroll 1
    for (int cc = 0; cc < 8; ++cc) {
        const int c0 = cc * 2;
        // even: compute c0 (buf0/A-regs), prefetch c0+1 (buf1/B-regs)
        LOADA(c0 + 1);
        LOADB(BhB, BlB, c0 + 1);
        COMPUTE(0, BhA, BlA);
        WRITEA(1);
        __syncthreads();
        // odd: compute c0+1, prefetch c0+2
        LOADA(c0 + 2);
        LOADB(BhA, BlA, c0 + 2);
        COMPUTE(1, BhB, BlB);
        WRITEA(0);
        __syncthreads();
    }
    COMPUTE(0, BhA, BlA);   // chunk 16 (x-part tail)

    // ---- epilogue: exchange gates via LDS ----
    // C frag: col = lane&31, row = (reg&3) + 8*(reg>>2) + 4*(lane>>5)
    {
        const int ccol = l & 31;
        const int rbase = 4 * (l >> 5);
#pragma unroll
        for (int r = 0; r < 16; ++r) {
            int rowi = (r & 3) + 8 * (r >> 2) + rbase;
            zs[w][rowi][ccol]      = acc0[r];
            zs[w][rowi][32 + ccol] = acc1[r];
        }
    }
    __syncthreads();

    {
        const int row = tid >> 3;        // 0..31
        const int u8  = tid & 7;         // 0..7 -> 8 units
        const long gr = row0 + row;
#pragma unroll
        for (int q = 0; q < 2; ++q) {
            const int ul = u8 * 8 + q * 4;
            const int ug = bu * 64 + ul;
            const long gidx = gr * Uq + ug;
            f32x4 zi = *(const f32x4*)&zs[0][row][ul];
            f32x4 zf = *(const f32x4*)&zs[1][row][ul];
            f32x4 zg = *(const f32x4*)&zs[2][row][ul];
            f32x4 zo = *(const f32x4*)&zs[3][row][ul];
            f32x4 cv = *(const f32x4*)(c_st + gidx);
            f32x4 hv;
#pragma unroll
            for (int j = 0; j < 4; ++j) {
                float vi = sigmoidf_(zi[j] + bias[0 * Uq + ug + j]);
                float vf = sigmoidf_(zf[j] + bias[1 * Uq + ug + j]);
                float vg = tanhf_  (zg[j] + bias[2 * Uq + ug + j]);
                float vo = sigmoidf_(zo[j] + bias[3 * Uq + ug + j]);
                float cn = vf * cv[j] + vi * vg;
                cv[j] = cn;
                hv[j] = vo * tanhf_(cn);
            }
            *(f32x4*)(c_st + gidx) = cv;
            *(f32x4*)(h_out + gidx) = hv;
        }
    }
}

// ---------------------------------------------------------------------------
// Dense readout p = h @ Wd + bd ; scatter into out[:, step, :].
// Block: 2 rows; threads: f = t&63, kq = t>>6 (K split by 4).
// ---------------------------------------------------------------------------
__global__ __launch_bounds__(256)
void readout(const float* __restrict__ h, const float* __restrict__ Wd,
             const float* __restrict__ bd, float* __restrict__ p,
             float* __restrict__ out, int step)
{
    __shared__ float red[2][4][64];
    const int t = threadIdx.x;
    const int f = t & 63, kq = t >> 6;
    const int r0 = blockIdx.x * 2;
    float s0 = 0.0f, s1 = 0.0f;
    const float* h0p = h + (long)r0 * Uq + kq * 256;
    const float* h1p = h0p + Uq;
    const float* wp  = Wd + (long)kq * 256 * Fq + f;
#pragma unroll 4
    for (int k = 0; k < 256; ++k) {
        float wv = wp[(long)k * Fq];
        s0 = fmaf(h0p[k], wv, s0);
        s1 = fmaf(h1p[k], wv, s1);
    }
    red[0][kq][f] = s0;
    red[1][kq][f] = s1;
    __syncthreads();
    if (t < 128) {
        int rr = t >> 6, ff = t & 63;
        float s = red[rr][0][ff] + red[rr][1][ff] + red[rr][2][ff] + red[rr][3][ff] + bd[ff];
        p[(long)(r0 + rr) * Fq + ff] = s;
        out[((long)(r0 + rr) * OSTEPS + step) * Fq + ff] = s;
    }
}

__global__ void zero2(float* __restrict__ a, float* __restrict__ b, int n) {
    int i = blockIdx.x * 256 + threadIdx.x;
    if (i < n) { a[i] = 0.0f; b[i] = 0.0f; }
}

extern "C" void kernel_launch(void* const* d_in, const int* in_sizes, int n_in,
                              void* d_out, int out_size, void* d_ws, size_t ws_size,
                              hipStream_t stream) {
    const float* inputs = (const float*)d_in[0];  // [512][128][64]
    const float* Wx     = (const float*)d_in[1];  // [64][4096]
    const float* Wh     = (const float*)d_in[2];  // [1024][4096]
    const float* b      = (const float*)d_in[3];  // [4096]
    const float* Wd     = (const float*)d_in[4];  // [1024][64]
    const float* bd     = (const float*)d_in[5];  // [64]
    float* out = (float*)d_out;

    // workspace layout (floats):
    float* ws = (float*)d_ws;
    float* h0 = ws;                       // 512*1024
    float* h1 = h0 + Bq * Uq;             // 512*1024
    float* c  = h1 + Bq * Uq;             // 512*1024
    float* p  = c  + Bq * Uq;             // 512*64
    bf16x8* BpH = (bf16x8*)(p + Bq * Fq);                 // 557056 * 16 B
    bf16x8* BpL = BpH + (long)128 * NKC16 * 64;           // 557056 * 16 B
    // total ~24.2 MB

    pack_w<<<(128 * NKC16 * 64) / 256, 256, 0, stream>>>(Wh, Wx, BpH, BpL);
    zero2<<<(Bq * Uq + 255) / 256, 256, 0, stream>>>(h0, c, Bq * Uq);

    float* hc = h0;
    float* hn = h1;
    // ---- warmup over T timesteps ----
    for (int t = 0; t < Tq; ++t) {
        lstm_step<<<256, 256, 0, stream>>>(hc, inputs + (long)t * Fq, (long)Tq * Fq,
                                           BpH, BpL, b, hn, c);
        float* tmp = hc; hc = hn; hn = tmp;
    }
    readout<<<Bq / 2, 256, 0, stream>>>(hc, Wd, bd, p, out, 0);
    // ---- autoregressive decode ----
    for (int s = 1; s < OSTEPS; ++s) {
        lstm_step<<<256, 256, 0, stream>>>(hc, p, (long)Fq, BpH, BpL, b, hn, c);
        float* tmp = hc; hc = hn; hn = tmp;
        readout<<<Bq / 2, 256, 0, stream>>>(hc, Wd, bd, p, out, s);
    }
}

// Round 3
// 2851.143 us; speedup vs baseline: 4.6701x; 1.3362x over previous
//
#include <hip/hip_runtime.h>
#include <math.h>

#define Bq 512
#define Tq 128
#define Fq 64
#define Uq 1024
#define OSTEPS 24
#define NKC16 68

typedef __bf16 bf16x8 __attribute__((ext_vector_type(8)));
typedef __bf16 bf16x4 __attribute__((ext_vector_type(4)));
typedef float f32x16 __attribute__((ext_vector_type(16)));
typedef float f32x4 __attribute__((ext_vector_type(4)));

__device__ __forceinline__ float sigmoidf_(float x) {
    return 1.0f / (1.0f + __expf(-x));
}
__device__ __forceinline__ float tanhf_(float x) {
    return 2.0f / (1.0f + __expf(-2.0f * x)) - 1.0f;
}

// ---------------------------------------------------------------------------
// Pack Wh [1024][4096] + Wx [64][4096] (fp32, z-col = g*1024+u) into B-fragment
// order for v_mfma_f32_32x32x16_bf16, split hi/lo bf16. (unchanged from r2)
// Bp[(gcol32*68 + kc16)*64 + lane]: gcol32 = g*32 + ublk; col = lane&31;
// k = kc16*16 + (lane>>5)*8 + j  (k<1024 -> Wh; else Wx row k-1024)
// ---------------------------------------------------------------------------
__global__ __launch_bounds__(256)
void pack_w(const float* __restrict__ Wh, const float* __restrict__ Wx,
            bf16x8* __restrict__ BpH, bf16x8* __restrict__ BpL)
{
    long id = (long)blockIdx.x * 256 + threadIdx.x;   // 128*68*64 slots
    int lane = (int)(id & 63);
    long rest = id >> 6;
    int kc16 = (int)(rest % NKC16);
    int gcol = (int)(rest / NKC16);                   // 0..127
    int col = (gcol >> 5) * Uq + (gcol & 31) * 32 + (lane & 31);
    int k0 = kc16 * 16 + (lane >> 5) * 8;
    bf16x8 hv, lv;
#pragma unroll
    for (int j = 0; j < 8; ++j) {
        int k = k0 + j;
        float v = (k < Uq) ? Wh[(long)k * (4 * Uq) + col]
                           : Wx[(long)(k - Uq) * (4 * Uq) + col];
        __bf16 h_ = (__bf16)v;
        hv[j] = h_;
        lv[j] = (__bf16)(v - (float)h_);
    }
    BpH[id] = hv;
    BpL[id] = lv;
}

// ---------------------------------------------------------------------------
// Fused LSTM step, MFMA bf16x3 split.
// Block: 64 batch rows x 32 units, 512 threads = 8 waves.
// Wave role: gate g = w&3, K-half kh = w>>2 (disjoint B loads across waves).
// Each wave: two 32x32 acc tiles (M-halves), partial over its K-half.
// Grid: 256 = 8 bm x 32 bu.
// ---------------------------------------------------------------------------
#define STAGE_LOAD(cn) do {                                                     \
    if ((cn) < 16) {                                                            \
        const __bf16* ph_ = hhi_in + (long)(row0 + srow) * Uq + (cn) * 64 + kg8 * 8; \
        const __bf16* pl_ = hlo_in + (long)(row0 + srow) * Uq + (cn) * 64 + kg8 * 8; \
        sh = *(const bf16x8*)ph_;                                               \
        sl = *(const bf16x8*)pl_;                                               \
    } else {                                                                    \
        const float* px_ = xsrc + (long)(row0 + srow) * xstride + kg8 * 8;      \
        f32x4 v0_ = *(const f32x4*)px_;                                         \
        f32x4 v1_ = *(const f32x4*)(px_ + 4);                                   \
        _Pragma("unroll")                                                       \
        for (int j_ = 0; j_ < 4; ++j_) { float v = v0_[j_]; __bf16 h_ = (__bf16)v; \
            sh[j_] = h_; sl[j_] = (__bf16)(v - (float)h_); }                    \
        _Pragma("unroll")                                                       \
        for (int j_ = 0; j_ < 4; ++j_) { float v = v1_[j_]; __bf16 h_ = (__bf16)v; \
            sh[4 + j_] = h_; sl[4 + j_] = (__bf16)(v - (float)h_); }            \
    }                                                                           \
} while (0)

#define STAGE_WRITE(nb) do {                                                    \
    As2[nb][0][smh][sslot] = sh;                                                \
    As2[nb][1][smh][sslot] = sl;                                                \
} while (0)

#define LOADB(BH, BL, c) do {                                                   \
    _Pragma("unroll")                                                           \
    for (int kc2_ = 0; kc2_ < 2; ++kc2_) {                                      \
        long idx_ = ((long)(g * 32 + bu) * NKC16 + (c) * 4 + kh * 2 + kc2_) * 64 + l; \
        BH[kc2_] = BpH[idx_];                                                   \
        BL[kc2_] = BpL[idx_];                                                   \
    }                                                                           \
} while (0)

#define COMPUTE(cb, BH, BL) do {                                                \
    _Pragma("unroll")                                                           \
    for (int kc2_ = 0; kc2_ < 2; ++kc2_) {                                      \
        const int kc_ = kh * 2 + kc2_;                                          \
        const int slot_ = (l & 31) * 8 + ((kc_ * 2 + (l >> 5)) ^ (l & 7));      \
        _Pragma("unroll")                                                       \
        for (int mh_ = 0; mh_ < 2; ++mh_) {                                     \
            bf16x8 ah_ = As2[cb][0][mh_][slot_];                                \
            bf16x8 al_ = As2[cb][1][mh_][slot_];                                \
            acc[mh_] = __builtin_amdgcn_mfma_f32_32x32x16_bf16(ah_, BH[kc2_], acc[mh_], 0, 0, 0); \
            acc[mh_] = __builtin_amdgcn_mfma_f32_32x32x16_bf16(al_, BH[kc2_], acc[mh_], 0, 0, 0); \
            acc[mh_] = __builtin_amdgcn_mfma_f32_32x32x16_bf16(ah_, BL[kc2_], acc[mh_], 0, 0, 0); \
        }                                                                       \
    }                                                                           \
} while (0)

__global__ __launch_bounds__(512, 2)
void lstm_step(const __bf16* __restrict__ hhi_in,   // [512][1024]
               const __bf16* __restrict__ hlo_in,
               const float* __restrict__ xsrc,      // fp32, 64 cols, stride xstride
               long xstride,
               const bf16x8* __restrict__ BpH,
               const bf16x8* __restrict__ BpL,
               const float* __restrict__ bias,      // [4096]
               __bf16* __restrict__ hhi_out,
               __bf16* __restrict__ hlo_out,
               float* __restrict__ c_st)            // [512][1024] fp32 in/out
{
    // union: A-staging frags (32 KB) then gate-exchange zsd (73.7 KB)
    __shared__ __align__(16) char smem[2 * 4 * 64 * 36 * 4];
    bf16x8 (*As2)[2][2][256] = (bf16x8 (*)[2][2][256])smem;   // [buf][hl][mh][slot]
    float (*zsd)[4][64][36] = (float (*)[4][64][36])smem;     // [kh][g][row][col]

    const int tid = threadIdx.x;
    const int l   = tid & 63;
    const int w   = tid >> 6;
    const int g   = w & 3;          // gate
    const int kh  = w >> 2;         // K-half
    const int bm  = (int)blockIdx.x >> 5;
    const int bu  = (int)blockIdx.x & 31;
    const int row0 = bm * 64;

    // staging decomposition: 64 rows x 8 k-octets
    const int srow = tid >> 3;      // 0..63
    const int kg8  = tid & 7;       // 0..7
    const int smh  = srow >> 5;
    const int sr31 = srow & 31;
    const int sslot = sr31 * 8 + (kg8 ^ (sr31 & 7));

    f32x16 acc[2];
#pragma unroll
    for (int i = 0; i < 16; ++i) { acc[0][i] = 0.0f; acc[1][i] = 0.0f; }

    bf16x8 BhA[2], BlA[2], BhB[2], BlB[2];
    bf16x8 sh, sl;

    // prologue: chunk 0
    STAGE_LOAD(0);
    LOADB(BhA, BlA, 0);
    STAGE_WRITE(0);
    __syncthreads();

#pragma unroll 1
    for (int cc = 0; cc < 8; ++cc) {
        const int c0 = cc * 2;
        // compute c0 (buf0, BA); stage c0+1 -> buf1; prefetch B(c0+1) -> BB
        STAGE_LOAD(c0 + 1);
        LOADB(BhB, BlB, c0 + 1);
        COMPUTE(0, BhA, BlA);
        STAGE_WRITE(1);
        __syncthreads();
        // compute c0+1 (buf1, BB); stage c0+2 -> buf0; prefetch B(c0+2) -> BA
        STAGE_LOAD(c0 + 2);
        LOADB(BhA, BlA, c0 + 2);
        COMPUTE(1, BhB, BlB);
        STAGE_WRITE(0);
        __syncthreads();
    }
    COMPUTE(0, BhA, BlA);   // chunk 16 (x tail)
    __syncthreads();        // As2 dead; smem becomes zsd

    // ---- K-half partial sums + gate exchange ----
    // C frag: col = l&31 (unit), row = (r&3) + 8*(r>>2) + 4*(l>>5) (batch)
#pragma unroll
    for (int mh_ = 0; mh_ < 2; ++mh_) {
#pragma unroll
        for (int r = 0; r < 16; ++r) {
            int rowi = mh_ * 32 + (r & 3) + 8 * (r >> 2) + 4 * (l >> 5);
            zsd[kh][g][rowi][l & 31] = acc[mh_][r];
        }
    }
    __syncthreads();

    // ---- fused gates + state update ----
    {
        const int row = tid >> 3;          // 0..63
        const int u4  = (tid & 7) * 4;     // 0..28
        const int grow = row0 + row;
        const int gu   = bu * 32 + u4;
        const long gidx = (long)grow * Uq + gu;
        f32x4 z0 = *(const f32x4*)&zsd[0][0][row][u4] + *(const f32x4*)&zsd[1][0][row][u4];
        f32x4 z1 = *(const f32x4*)&zsd[0][1][row][u4] + *(const f32x4*)&zsd[1][1][row][u4];
        f32x4 z2 = *(const f32x4*)&zsd[0][2][row][u4] + *(const f32x4*)&zsd[1][2][row][u4];
        f32x4 z3 = *(const f32x4*)&zsd[0][3][row][u4] + *(const f32x4*)&zsd[1][3][row][u4];
        f32x4 bi = *(const f32x4*)(bias + 0 * Uq + gu);
        f32x4 bf_ = *(const f32x4*)(bias + 1 * Uq + gu);
        f32x4 bg = *(const f32x4*)(bias + 2 * Uq + gu);
        f32x4 bo = *(const f32x4*)(bias + 3 * Uq + gu);
        f32x4 cv = *(const f32x4*)(c_st + gidx);
        bf16x4 hh, hl4;
#pragma unroll
        for (int j = 0; j < 4; ++j) {
            float vi = sigmoidf_(z0[j] + bi[j]);
            float vf = sigmoidf_(z1[j] + bf_[j]);
            float vg = tanhf_  (z2[j] + bg[j]);
            float vo = sigmoidf_(z3[j] + bo[j]);
            float cn = vf * cv[j] + vi * vg;
            cv[j] = cn;
            float hval = vo * tanhf_(cn);
            __bf16 h_ = (__bf16)hval;
            hh[j] = h_;
            hl4[j] = (__bf16)(hval - (float)h_);
        }
        *(f32x4*)(c_st + gidx) = cv;
        *(bf16x4*)(hhi_out + gidx) = hh;
        *(bf16x4*)(hlo_out + gidx) = hl4;
    }
}

// ---------------------------------------------------------------------------
// Dense readout p = (hhi+hlo) @ Wd + bd ; scatter into out[:, step, :].
// ---------------------------------------------------------------------------
__global__ __launch_bounds__(256)
void readout(const __bf16* __restrict__ hhi, const __bf16* __restrict__ hlo,
             const float* __restrict__ Wd, const float* __restrict__ bd,
             float* __restrict__ p, float* __restrict__ out, int step)
{
    __shared__ float red[2][4][64];
    const int t = threadIdx.x;
    const int f = t & 63, kq = t >> 6;
    const int r0 = blockIdx.x * 2;
    float s0 = 0.0f, s1 = 0.0f;
    const __bf16* h0h = hhi + (long)r0 * Uq + kq * 256;
    const __bf16* h0l = hlo + (long)r0 * Uq + kq * 256;
    const float* wp = Wd + (long)kq * 256 * Fq + f;
#pragma unroll 4
    for (int i = 0; i < 32; ++i) {
        bf16x8 ah = *(const bf16x8*)(h0h + i * 8);
        bf16x8 al = *(const bf16x8*)(h0l + i * 8);
        bf16x8 bh = *(const bf16x8*)(h0h + Uq + i * 8);
        bf16x8 bl = *(const bf16x8*)(h0l + Uq + i * 8);
#pragma unroll
        for (int j = 0; j < 8; ++j) {
            float wv = wp[(long)(i * 8 + j) * Fq];
            s0 = fmaf((float)ah[j] + (float)al[j], wv, s0);
            s1 = fmaf((float)bh[j] + (float)bl[j], wv, s1);
        }
    }
    red[0][kq][f] = s0;
    red[1][kq][f] = s1;
    __syncthreads();
    if (t < 128) {
        int rr = t >> 6, ff = t & 63;
        float s = red[rr][0][ff] + red[rr][1][ff] + red[rr][2][ff] + red[rr][3][ff] + bd[ff];
        p[(long)(r0 + rr) * Fq + ff] = s;
        out[((long)(r0 + rr) * OSTEPS + step) * Fq + ff] = s;
    }
}

__global__ void zero_ws(f32x4* __restrict__ a, int n) {
    int i = blockIdx.x * 256 + threadIdx.x;
    f32x4 z = {0.0f, 0.0f, 0.0f, 0.0f};
    if (i < n) a[i] = z;
}

extern "C" void kernel_launch(void* const* d_in, const int* in_sizes, int n_in,
                              void* d_out, int out_size, void* d_ws, size_t ws_size,
                              hipStream_t stream) {
    const float* inputs = (const float*)d_in[0];  // [512][128][64]
    const float* Wx     = (const float*)d_in[1];  // [64][4096]
    const float* Wh     = (const float*)d_in[2];  // [1024][4096]
    const float* b      = (const float*)d_in[3];  // [4096]
    const float* Wd     = (const float*)d_in[4];  // [1024][64]
    const float* bd     = (const float*)d_in[5];  // [64]
    float* out = (float*)d_out;

    // workspace layout: c | Hhi0 | Hlo0 | Hhi1 | Hlo1 | p | BpH | BpL
    float* ws = (float*)d_ws;
    float* c_st = ws;                              // 512*1024 f32 (2 MB)
    __bf16* Hhi0 = (__bf16*)(ws + Bq * Uq);        // 1 MB each
    __bf16* Hlo0 = Hhi0 + Bq * Uq;
    __bf16* Hhi1 = Hlo0 + Bq * Uq;
    __bf16* Hlo1 = Hhi1 + Bq * Uq;
    float* p = (float*)(Hlo1 + Bq * Uq);           // 512*64 f32
    bf16x8* BpH = (bf16x8*)(p + Bq * Fq);          // 557056 * 16 B
    bf16x8* BpL = BpH + (long)128 * NKC16 * 64;

    pack_w<<<(128 * NKC16 * 64) / 256, 256, 0, stream>>>(Wh, Wx, BpH, BpL);
    // zero c + Hhi0 + Hlo0 (contiguous 4 MB)
    zero_ws<<<1024, 256, 0, stream>>>((f32x4*)ws, (Bq * Uq * 4 + Bq * Uq * 2 * 2 / 4) / 4);

    __bf16 *hhi_c = Hhi0, *hlo_c = Hlo0, *hhi_n = Hhi1, *hlo_n = Hlo1;
    // ---- warmup over T timesteps ----
    for (int t = 0; t < Tq; ++t) {
        lstm_step<<<256, 512, 0, stream>>>(hhi_c, hlo_c,
                                           inputs + (long)t * Fq, (long)Tq * Fq,
                                           BpH, BpL, b, hhi_n, hlo_n, c_st);
        __bf16* tmp;
        tmp = hhi_c; hhi_c = hhi_n; hhi_n = tmp;
        tmp = hlo_c; hlo_c = hlo_n; hlo_n = tmp;
    }
    readout<<<Bq / 2, 256, 0, stream>>>(hhi_c, hlo_c, Wd, bd, p, out, 0);
    // ---- autoregressive decode ----
    for (int s = 1; s < OSTEPS; ++s) {
        lstm_step<<<256, 512, 0, stream>>>(hhi_c, hlo_c, p, (long)Fq,
                                           BpH, BpL, b, hhi_n, hlo_n, c_st);
        __bf16* tmp;
        tmp = hhi_c; hhi_c = hhi_n; hhi_n = tmp;
        tmp = hlo_c; hlo_c = hlo_n; hlo_n = tmp;
        readout<<<Bq / 2, 256, 0, stream>>>(hhi_c, hlo_c, Wd, bd, p, out, s);
    }
}

// Round 5
// 2821.952 us; speedup vs baseline: 4.7184x; 1.0103x over previous
//
#include <hip/hip_runtime.h>
#include <math.h>

#define Bq 512
#define Tq 128
#define Fq 64
#define Uq 1024
#define OSTEPS 24
#define NKC16 68

typedef __bf16 bf16x8 __attribute__((ext_vector_type(8)));
typedef __bf16 bf16x4 __attribute__((ext_vector_type(4)));
typedef __bf16 bf16x2 __attribute__((ext_vector_type(2)));
typedef float f32x16 __attribute__((ext_vector_type(16)));
typedef float f32x4 __attribute__((ext_vector_type(4)));
typedef float f32x2 __attribute__((ext_vector_type(2)));

__device__ __forceinline__ float sigmoidf_(float x) {
    return 1.0f / (1.0f + __expf(-x));
}
__device__ __forceinline__ float tanhf_(float x) {
    return 2.0f / (1.0f + __expf(-2.0f * x)) - 1.0f;
}

// barrier WITHOUT vmcnt drain: LDS-complete + hw barrier; global loads stay in flight
#define BAR() do {                                             \
    asm volatile("s_waitcnt lgkmcnt(0)" ::: "memory");         \
    __builtin_amdgcn_s_barrier();                              \
} while (0)

// ---------------------------------------------------------------------------
// Pack Wh [1024][4096] + Wx [64][4096] (fp32, z-col = g*1024+u) into B-fragment
// order for v_mfma_f32_32x32x16_bf16, split hi/lo bf16. (unchanged, verified)
// Bp[(gcol32*68 + kc16)*64 + lane]: gcol32 = g*32 + ublk; col = lane&31;
// k = kc16*16 + (lane>>5)*8 + j  (k<1024 -> Wh; else Wx row k-1024)
// ---------------------------------------------------------------------------
__global__ __launch_bounds__(256)
void pack_w(const float* __restrict__ Wh, const float* __restrict__ Wx,
            bf16x8* __restrict__ BpH, bf16x8* __restrict__ BpL)
{
    long id = (long)blockIdx.x * 256 + threadIdx.x;   // 128*68*64 slots
    int lane = (int)(id & 63);
    long rest = id >> 6;
    int kc16 = (int)(rest % NKC16);
    int gcol = (int)(rest / NKC16);                   // 0..127
    int col = (gcol >> 5) * Uq + (gcol & 31) * 32 + (lane & 31);
    int k0 = kc16 * 16 + (lane >> 5) * 8;
    bf16x8 hv, lv;
#pragma unroll
    for (int j = 0; j < 8; ++j) {
        int k = k0 + j;
        float v = (k < Uq) ? Wh[(long)k * (4 * Uq) + col]
                           : Wx[(long)(k - Uq) * (4 * Uq) + col];
        __bf16 h_ = (__bf16)v;
        hv[j] = h_;
        lv[j] = (__bf16)(v - (float)h_);
    }
    BpH[id] = hv;
    BpL[id] = lv;
}

// ---------------------------------------------------------------------------
// Fused LSTM step, MFMA bf16x3 split, software-pipelined (depth-2 prefetch,
// no-vmcnt-drain barriers, fully unrolled 17-chunk K loop).
// Block: 64 batch rows x 32 units, 512 threads = 8 waves.
// Wave role: gate-pair gp = w&1 (gates 2gp,2gp+1), K-quarter kq = w>>1.
// Each wave: acc[2 gates][2 mh] 32x32 tiles, partial over its K-quarter.
// Grid: 256 = 8 bm x 32 bu (natural: same bu -> same XCD -> B shared via L2).
// ---------------------------------------------------------------------------
#define STAGE_LOAD(c, j) do {                                                   \
    if ((c) < 16) {                                                             \
        ash[j] = *(const bf16x8*)(hrow_hi + (c) * 64);                          \
        asl[j] = *(const bf16x8*)(hrow_lo + (c) * 64);                          \
    } else {                                                                    \
        f32x4 v0_ = *(const f32x4*)xrow;                                        \
        f32x4 v1_ = *(const f32x4*)(xrow + 4);                                  \
        bf16x8 hv_, lv_;                                                        \
        _Pragma("unroll")                                                       \
        for (int j_ = 0; j_ < 4; ++j_) { float v = v0_[j_]; __bf16 h_ = (__bf16)v; \
            hv_[j_] = h_; lv_[j_] = (__bf16)(v - (float)h_); }                  \
        _Pragma("unroll")                                                       \
        for (int j_ = 0; j_ < 4; ++j_) { float v = v1_[j_]; __bf16 h_ = (__bf16)v; \
            hv_[4 + j_] = h_; lv_[4 + j_] = (__bf16)(v - (float)h_); }          \
        ash[j] = hv_; asl[j] = lv_;                                             \
    }                                                                           \
} while (0)

#define STAGE_WRITE(nb, j) do {                                                 \
    As2[nb][0][smh][sslot] = ash[j];                                            \
    As2[nb][1][smh][sslot] = asl[j];                                            \
} while (0)

#define LOADB(s, c) do {                                                        \
    Bh[s][0] = bpH0[((c) * 4 + kq) * 64];                                       \
    Bl[s][0] = bpL0[((c) * 4 + kq) * 64];                                       \
    Bh[s][1] = bpH1[((c) * 4 + kq) * 64];                                       \
    Bl[s][1] = bpL1[((c) * 4 + kq) * 64];                                       \
} while (0)

#define COMPUTE(cb, si) do {                                                    \
    bf16x8 ah0_ = As2[cb][0][0][rdslot];                                        \
    bf16x8 al0_ = As2[cb][1][0][rdslot];                                        \
    bf16x8 ah1_ = As2[cb][0][1][rdslot];                                        \
    bf16x8 al1_ = As2[cb][1][1][rdslot];                                        \
    __builtin_amdgcn_s_setprio(1);                                              \
    _Pragma("unroll")                                                           \
    for (int g2_ = 0; g2_ < 2; ++g2_) {                                         \
        acc[g2_][0] = __builtin_amdgcn_mfma_f32_32x32x16_bf16(ah0_, Bh[si][g2_], acc[g2_][0], 0, 0, 0); \
        acc[g2_][0] = __builtin_amdgcn_mfma_f32_32x32x16_bf16(al0_, Bh[si][g2_], acc[g2_][0], 0, 0, 0); \
        acc[g2_][0] = __builtin_amdgcn_mfma_f32_32x32x16_bf16(ah0_, Bl[si][g2_], acc[g2_][0], 0, 0, 0); \
        acc[g2_][1] = __builtin_amdgcn_mfma_f32_32x32x16_bf16(ah1_, Bh[si][g2_], acc[g2_][1], 0, 0, 0); \
        acc[g2_][1] = __builtin_amdgcn_mfma_f32_32x32x16_bf16(al1_, Bh[si][g2_], acc[g2_][1], 0, 0, 0); \
        acc[g2_][1] = __builtin_amdgcn_mfma_f32_32x32x16_bf16(ah1_, Bl[si][g2_], acc[g2_][1], 0, 0, 0); \
    }                                                                           \
    __builtin_amdgcn_s_setprio(0);                                              \
} while (0)

__global__ __launch_bounds__(512, 2)
void lstm_step(const __bf16* __restrict__ hhi_in,   // [512][1024]
               const __bf16* __restrict__ hlo_in,
               const float* __restrict__ xsrc,      // fp32, 64 cols, stride xstride
               long xstride,
               const bf16x8* __restrict__ BpH,
               const bf16x8* __restrict__ BpL,
               const float* __restrict__ bias,      // [4096]
               __bf16* __restrict__ hhi_out,
               __bf16* __restrict__ hlo_out,
               float* __restrict__ c_st)            // [512][1024] fp32 in/out
{
    // union: A-staging frags (32 KB) then gate-exchange zsd (72 KB)
    __shared__ __align__(16) char smem[4 * 4 * 32 * 36 * 4];
    bf16x8 (*As2)[2][2][256] = (bf16x8 (*)[2][2][256])smem;   // [buf][plane][mh][slot]
    float (*zsd)[4][32][36] = (float (*)[4][32][36])smem;     // [kq][g][row][col]

    const int tid = threadIdx.x;
    const int l   = tid & 63;
    const int w   = tid >> 6;
    const int gp  = w & 1;          // gate pair: gates 2gp, 2gp+1
    const int kq  = w >> 1;         // K-quarter 0..3
    const int bm  = (int)blockIdx.x >> 5;
    const int bu  = (int)blockIdx.x & 31;
    const int row0 = bm * 64;

    // staging decomposition: 64 rows x 8 k-octets (identical to verified r3)
    const int srow = tid >> 3;      // 0..63
    const int kg8  = tid & 7;       // 0..7
    const int smh  = srow >> 5;
    const int sr31 = srow & 31;
    const int sslot = sr31 * 8 + (kg8 ^ (sr31 & 7));

    // fragment read slot (kc = kq), loop-invariant
    const int rdslot = (l & 31) * 8 + ((kq * 2 + (l >> 5)) ^ (l & 7));

    // per-wave global base pointers
    const bf16x8* bpH0 = BpH + ((long)((gp * 2 + 0) * 32 + bu) * NKC16) * 64 + l;
    const bf16x8* bpL0 = BpL + ((long)((gp * 2 + 0) * 32 + bu) * NKC16) * 64 + l;
    const bf16x8* bpH1 = BpH + ((long)((gp * 2 + 1) * 32 + bu) * NKC16) * 64 + l;
    const bf16x8* bpL1 = BpL + ((long)((gp * 2 + 1) * 32 + bu) * NKC16) * 64 + l;
    const __bf16* hrow_hi = hhi_in + (long)(row0 + srow) * Uq + kg8 * 8;
    const __bf16* hrow_lo = hlo_in + (long)(row0 + srow) * Uq + kg8 * 8;
    const float*  xrow    = xsrc + (long)(row0 + srow) * xstride + kg8 * 8;

    f32x16 acc[2][2];
#pragma unroll
    for (int i = 0; i < 16; ++i) {
        acc[0][0][i] = 0.0f; acc[0][1][i] = 0.0f;
        acc[1][0][i] = 0.0f; acc[1][1][i] = 0.0f;
    }

    bf16x8 Bh[3][2], Bl[3][2];
    bf16x8 ash[2], asl[2];

    // ---- prologue ----
    STAGE_LOAD(0, 0);
    STAGE_LOAD(1, 1);
    LOADB(0, 0);
    LOADB(1, 1);
    STAGE_WRITE(0, 0);
    BAR();

    // ---- fully-unrolled pipelined K loop: 17 chunks ----
#pragma unroll
    for (int i = 0; i < 17; ++i) {
        if (i <= 14) {
            LOADB((i + 2) % 3, i + 2);
            STAGE_LOAD(i + 2, i & 1);        // (i+2)&1 == i&1
        }
        if (i <= 15) STAGE_WRITE((i + 1) & 1, (i + 1) & 1);
        COMPUTE(i & 1, i % 3);
        if (i < 16) BAR();
    }

    BAR();   // all fragment reads retired; smem becomes zsd

    // ---- epilogue: two passes over M-halves ----
#pragma unroll
    for (int mh = 0; mh < 2; ++mh) {
        // write partials: zsd[kq][gate][row][unit]
#pragma unroll
        for (int g2 = 0; g2 < 2; ++g2)
#pragma unroll
            for (int r = 0; r < 16; ++r) {
                int rowi = (r & 3) + 8 * (r >> 2) + 4 * (l >> 5);
                zsd[kq][gp * 2 + g2][rowi][l & 31] = acc[g2][mh][r];
            }
        BAR();
        // reduce 4 K-quarters + gates + state update (32 rows x 32 units)
        {
            const int row = tid >> 4;          // 0..31
            const int uu  = (tid & 15) * 2;    // 0..30
            const int grow = row0 + mh * 32 + row;
            const int gu   = bu * 32 + uu;
            const long gidx = (long)grow * Uq + gu;
            float z[4][2];
#pragma unroll
            for (int g = 0; g < 4; ++g) {
#pragma unroll
                for (int j = 0; j < 2; ++j)
                    z[g][j] = zsd[0][g][row][uu + j] + zsd[1][g][row][uu + j]
                            + zsd[2][g][row][uu + j] + zsd[3][g][row][uu + j];
            }
            f32x2 cv = *(const f32x2*)(c_st + gidx);
            bf16x2 hh, hl2;
#pragma unroll
            for (int j = 0; j < 2; ++j) {
                float vi = sigmoidf_(z[0][j] + bias[0 * Uq + gu + j]);
                float vf = sigmoidf_(z[1][j] + bias[1 * Uq + gu + j]);
                float vg = tanhf_  (z[2][j] + bias[2 * Uq + gu + j]);
                float vo = sigmoidf_(z[3][j] + bias[3 * Uq + gu + j]);
                float cn = vf * cv[j] + vi * vg;
                cv[j] = cn;
                float hval = vo * tanhf_(cn);
                __bf16 h_ = (__bf16)hval;
                hh[j] = h_;
                hl2[j] = (__bf16)(hval - (float)h_);
            }
            *(f32x2*)(c_st + gidx) = cv;
            *(bf16x2*)(hhi_out + gidx) = hh;
            *(bf16x2*)(hlo_out + gidx) = hl2;
        }
        if (mh == 0) BAR();   // pass-1 reads done before pass-2 overwrites zsd
    }
}

// ---------------------------------------------------------------------------
// Dense readout p = (hhi+hlo) @ Wd + bd ; scatter into out[:, step, :].
// ---------------------------------------------------------------------------
__global__ __launch_bounds__(256)
void readout(const __bf16* __restrict__ hhi, const __bf16* __restrict__ hlo,
             const float* __restrict__ Wd, const float* __restrict__ bd,
             float* __restrict__ p, float* __restrict__ out, int step)
{
    __shared__ float red[2][4][64];
    const int t = threadIdx.x;
    const int f = t & 63, kq = t >> 6;
    const int r0 = blockIdx.x * 2;
    float s0 = 0.0f, s1 = 0.0f;
    const __bf16* h0h = hhi + (long)r0 * Uq + kq * 256;
    const __bf16* h0l = hlo + (long)r0 * Uq + kq * 256;
    const float* wp = Wd + (long)kq * 256 * Fq + f;
#pragma unroll 4
    for (int i = 0; i < 32; ++i) {
        bf16x8 ah = *(const bf16x8*)(h0h + i * 8);
        bf16x8 al = *(const bf16x8*)(h0l + i * 8);
        bf16x8 bh = *(const bf16x8*)(h0h + Uq + i * 8);
        bf16x8 bl = *(const bf16x8*)(h0l + Uq + i * 8);
#pragma unroll
        for (int j = 0; j < 8; ++j) {
            float wv = wp[(long)(i * 8 + j) * Fq];
            s0 = fmaf((float)ah[j] + (float)al[j], wv, s0);
            s1 = fmaf((float)bh[j] + (float)bl[j], wv, s1);
        }
    }
    red[0][kq][f] = s0;
    red[1][kq][f] = s1;
    __syncthreads();
    if (t < 128) {
        int rr = t >> 6, ff = t & 63;
        float s = red[rr][0][ff] + red[rr][1][ff] + red[rr][2][ff] + red[rr][3][ff] + bd[ff];
        p[(long)(r0 + rr) * Fq + ff] = s;
        out[((long)(r0 + rr) * OSTEPS + step) * Fq + ff] = s;
    }
}

__global__ void zero_ws(f32x4* __restrict__ a, int n) {
    int i = blockIdx.x * 256 + threadIdx.x;
    f32x4 z = {0.0f, 0.0f, 0.0f, 0.0f};
    if (i < n) a[i] = z;
}

extern "C" void kernel_launch(void* const* d_in, const int* in_sizes, int n_in,
                              void* d_out, int out_size, void* d_ws, size_t ws_size,
                              hipStream_t stream) {
    const float* inputs = (const float*)d_in[0];  // [512][128][64]
    const float* Wx     = (const float*)d_in[1];  // [64][4096]
    const float* Wh     = (const float*)d_in[2];  // [1024][4096]
    const float* b      = (const float*)d_in[3];  // [4096]
    const float* Wd     = (const float*)d_in[4];  // [1024][64]
    const float* bd     = (const float*)d_in[5];  // [64]
    float* out = (float*)d_out;

    // workspace layout: c | Hhi0 | Hlo0 | Hhi1 | Hlo1 | p | BpH | BpL
    float* ws = (float*)d_ws;
    float* c_st = ws;                              // 512*1024 f32 (2 MB)
    __bf16* Hhi0 = (__bf16*)(ws + Bq * Uq);        // 1 MB each
    __bf16* Hlo0 = Hhi0 + Bq * Uq;
    __bf16* Hhi1 = Hlo0 + Bq * Uq;
    __bf16* Hlo1 = Hhi1 + Bq * Uq;
    float* p = (float*)(Hlo1 + Bq * Uq);           // 512*64 f32
    bf16x8* BpH = (bf16x8*)(p + Bq * Fq);          // 557056 * 16 B
    bf16x8* BpL = BpH + (long)128 * NKC16 * 64;

    pack_w<<<(128 * NKC16 * 64) / 256, 256, 0, stream>>>(Wh, Wx, BpH, BpL);
    // zero c + Hhi0 + Hlo0 (contiguous 4 MB)
    zero_ws<<<1024, 256, 0, stream>>>((f32x4*)ws, 262144);

    __bf16 *hhi_c = Hhi0, *hlo_c = Hlo0, *hhi_n = Hhi1, *hlo_n = Hlo1;
    // ---- warmup over T timesteps ----
    for (int t = 0; t < Tq; ++t) {
        lstm_step<<<256, 512, 0, stream>>>(hhi_c, hlo_c,
                                           inputs + (long)t * Fq, (long)Tq * Fq,
                                           BpH, BpL, b, hhi_n, hlo_n, c_st);
        __bf16* tmp;
        tmp = hhi_c; hhi_c = hhi_n; hhi_n = tmp;
        tmp = hlo_c; hlo_c = hlo_n; hlo_n = tmp;
    }
    readout<<<Bq / 2, 256, 0, stream>>>(hhi_c, hlo_c, Wd, bd, p, out, 0);
    // ---- autoregressive decode ----
    for (int s = 1; s < OSTEPS; ++s) {
        lstm_step<<<256, 512, 0, stream>>>(hhi_c, hlo_c, p, (long)Fq,
                                           BpH, BpL, b, hhi_n, hlo_n, c_st);
        __bf16* tmp;
        tmp = hhi_c; hhi_c = hhi_n; hhi_n = tmp;
        tmp = hlo_c; hlo_c = hlo_n; hlo_n = tmp;
        readout<<<Bq / 2, 256, 0, stream>>>(hhi_c, hlo_c, Wd, bd, p, out, s);
    }
}